// Round 7
// baseline (245.207 us; speedup 1.0000x reference)
//
#include <hip/hip_runtime.h>
#include <hip/hip_bf16.h>

#define HWHW 65536   // 256*256
#define LN1E4_32 0.28782313662425572f   // ln(10000)/32
#define TWO_PI_N 6.2831847f              // 2*pi / 1.000001

typedef __attribute__((ext_vector_type(8))) short short8;
typedef __attribute__((ext_vector_type(4))) short s16x4;   // 'short4' taken by HIP
typedef __attribute__((ext_vector_type(4))) float f32x4;

// d_ws layout:
//   [0, 32768)        : wfrag bf16 — Q slots 0..1023 (K=128), K' 1024..1535,
//                       V' 1536..2047 (K=64, pair-summed weights)
//   [32768, 34816)    : bias tables fp32 — peK·Wk+k_b [4][64], then peV·Wv+v_b
//   [65536, 16842752) : feat_supp transposed (B,HW,C) bf16
// REQUIRES ws_size >= 16842752.

__device__ __forceinline__ short f2bf(float f) {
  union { __hip_bfloat16 h; short s; } u;
  u.h = __float2bfloat16(f);
  return u.s;
}

// ---------------- merged pre-pass:
//   blocks 0..511  : feat_supp (B,C,HW) f32 -> (B,HW,C) bf16 transpose
//   blocks 512..519: weight fragment packing
//   block  520     : PE-folded bias tables
__global__ __launch_bounds__(256)
void pre_pass(const float* __restrict__ supp,
              const float* __restrict__ qw, const float* __restrict__ kw,
              const float* __restrict__ vw,
              const float* __restrict__ kb, const float* __restrict__ vb,
              __hip_bfloat16* __restrict__ suppT,
              __hip_bfloat16* __restrict__ wfrag, float* __restrict__ bias) {
  const int t = threadIdx.x;
  if (blockIdx.x < 512) {
    // ---- transpose: 256 px x 64 ch per block. LDS row stride 68 shorts:
    // 34 dwords == 2 (mod 32) -> write banks 2-way (free); b64 reads ~4-way.
    __shared__ short tile[256 * 68];
    int b  = blockIdx.x >> 8;
    int p0 = (blockIdx.x & 255) << 8;
#pragma unroll
    for (int cg = 0; cg < 16; ++cg) {
      s16x4 v;
#pragma unroll
      for (int j = 0; j < 4; ++j)
        v[j] = f2bf(supp[((size_t)b * 64 + cg * 4 + j) * HWHW + p0 + t]);
      *(s16x4*)&tile[t * 68 + cg * 4] = v;
    }
    __syncthreads();
#pragma unroll
    for (int i = 0; i < 4; ++i) {
      int pl = i * 64 + (t >> 2);
      int ch = (t & 3) * 16;
      s16x4 r0 = *(s16x4*)&tile[pl * 68 + ch];
      s16x4 r1 = *(s16x4*)&tile[pl * 68 + ch + 4];
      s16x4 r2 = *(s16x4*)&tile[pl * 68 + ch + 8];
      s16x4 r3 = *(s16x4*)&tile[pl * 68 + ch + 12];
      short8 o0, o1;
#pragma unroll
      for (int j = 0; j < 4; ++j) {
        o0[j] = r0[j]; o0[j + 4] = r1[j];
        o1[j] = r2[j]; o1[j + 4] = r3[j];
      }
      short8* dst = (short8*)(suppT + ((size_t)(b * HWHW + p0 + pl)) * 64 + ch);
      dst[0] = o0;
      dst[1] = o1;
    }
  } else if (blockIdx.x < 520) {
    // ---- weight fragments. B layout: n=nt*16+(lane&15), k=ks*32+(lane>>4)*8+j
    int slot = (blockIdx.x - 512) * 256 + t;      // 0..2047
    __hip_bfloat16* dst = wfrag + slot * 8;
    if (slot < 1024) {               // Q (K=128)
      int ksnt = slot >> 6, lane = slot & 63;
      int ks = ksnt >> 2, nt = ksnt & 3;
      const float* w = qw + (nt * 16 + (lane & 15)) * 128 + ks * 32 + (lane >> 4) * 8;
#pragma unroll
      for (int j = 0; j < 8; ++j) dst[j] = __float2bfloat16(w[j]);
    } else {                         // K'/V': K=64, W'[n][c] = W[n][2c]+W[n][2c+1]
      int mat = (slot >= 1536);
      int rem = slot & 511;
      int ksnt = rem >> 6, lane = rem & 63;
      int ks = ksnt >> 2, nt = ksnt & 3;          // ks 0..1
      int c0 = ks * 32 + (lane >> 4) * 8;
      const float* w = (mat ? vw : kw) + (nt * 16 + (lane & 15)) * 128;
#pragma unroll
      for (int j = 0; j < 8; ++j)
        dst[j] = __float2bfloat16(w[2 * (c0 + j)] + w[2 * (c0 + j) + 1]);
    }
  } else {
    // ---- bias[mat*256 + uv*64 + c] = b[c] + sum_kk pe[uv][kk] * W[c][kk]
    for (int s = t; s < 512; s += 256) {
      int mat = s >> 8, uv = (s >> 6) & 3, c = s & 63;
      const float* w = (mat ? vw : kw) + c * 128;
      float acc = (mat ? vb : kb)[c];
      for (int kk = 0; kk < 128; ++kk) {
        float val = (kk < 64 ? (float)(uv >> 1) : (float)(uv & 1)) * TWO_PI_N;
        int i = kk & 63, f = i >> 1;
        float arg = val * __expf(-(float)f * LN1E4_32);
        float pe = (i & 1) ? __cosf(arg) : __sinf(arg);
        acc += pe * w[kk];
      }
      bias[s] = acc;
    }
  }
}

// ---------------- main: 64 px/block, 4 waves. 32 KB wfrag LDS (outstage aliased).
// waves_per_eu(4,4): VGPR cap 128 >= current 84 (no spill), 4 blocks/CU -> 50% occ.
// ((3,3) measured 26% occ / 82 us; unbounded max in R2/R3 spilled 580 MB.)
__global__ __attribute__((amdgpu_waves_per_eu(4, 4))) __launch_bounds__(256)
void iw_main(const __hip_bfloat16* __restrict__ suppT, const float* __restrict__ flow,
             const float* __restrict__ feat_curr,
             const f32x4* __restrict__ wfrag_g, const float* __restrict__ bias_g,
             const float* __restrict__ q_b, float* __restrict__ out)
{
  __shared__ __align__(16) unsigned char smem[32768];   // wfrag bf16 | outstage f32
  const short8* wfrag = (const short8*)smem;

  const int tid = threadIdx.x;
  const int idx = ((blockIdx.x & 7) << 8) | (blockIdx.x >> 3);  // XCD swizzle
  const int b   = idx >> 10;
  const int hw0 = (idx & 1023) << 6;
  const int lane = tid & 63, wv = tid >> 6;
  const int quad = lane >> 4, l15 = lane & 15;

  // stage weight fragments global -> LDS (32 KB, 16 B/lane coalesced)
  {
    f32x4* dst = (f32x4*)smem;
#pragma unroll
    for (int i = 0; i < 8; ++i) dst[i * 256 + tid] = wfrag_g[i * 256 + tid];
  }
  __syncthreads();

  // PE-folded K/V biases: kbr[r][nt] for output row uv=r, channel c=nt*16+l15
  float kbr[4][4], vbr[4][4];
#pragma unroll
  for (int r = 0; r < 4; ++r)
#pragma unroll
    for (int nt = 0; nt < 4; ++nt) {
      kbr[r][nt] = bias_g[r * 64 + nt * 16 + l15];
      vbr[r][nt] = bias_g[256 + r * 64 + nt * 16 + l15];
    }

  // per-lane inverse dim_t: f = a*16 + quad*4 + jj
  float invd[2][4];
#pragma unroll
  for (int a = 0; a < 2; ++a)
#pragma unroll
    for (int jj = 0; jj < 4; ++jj)
      invd[a][jj] = __expf(-(float)(a * 16 + quad * 4 + jj) * LN1E4_32);

  // ---------- Q phase: A-frag (m = l15 -> pixel), GEMM (K=128)
  f32x4 qacc[4];
  {
    const int qpix = hw0 + wv * 16 + l15;
    float2 fl = ((const float2*)flow)[b * HWHW + qpix];
    float gy = (float)(qpix >> 8) + fl.y;
    float gx = (float)(qpix & 255) + fl.x;
    float vy = (gy - floorf(gy)) * (6.2831853071795864f / 2.000001f);
    float vx = (gx - floorf(gx)) * (6.2831853071795864f / 2.000001f);

    short8 qa[4];
#pragma unroll
    for (int ks = 0; ks < 4; ++ks) {
      float val = (ks < 2) ? vy : vx;
#pragma unroll
      for (int jj = 0; jj < 4; ++jj) {
        int c = ks * 16 + quad * 4 + jj;
        float feat = feat_curr[(b * 64 + c) * HWHW + qpix];
        float arg = val * invd[ks & 1][jj];
        qa[ks][jj * 2]     = f2bf(feat + __sinf(arg));
        qa[ks][jj * 2 + 1] = f2bf(feat + __cosf(arg));
      }
    }
#pragma unroll
    for (int nt = 0; nt < 4; ++nt) qacc[nt] = (f32x4){0.f, 0.f, 0.f, 0.f};
#pragma unroll
    for (int ks = 0; ks < 4; ++ks)
#pragma unroll
      for (int nt = 0; nt < 4; ++nt)
        qacc[nt] = __builtin_amdgcn_mfma_f32_16x16x32_bf16(
            qa[ks], wfrag[(ks * 4 + nt) * 64 + lane], qacc[nt], 0, 0, 0);
  }

  // bias+scale then shuffle-transpose: qT[mt][nt] = q[pixel mt*4+quad][nt*16+l15]
  float qT[4][4];
  {
#pragma unroll
    for (int nt = 0; nt < 4; ++nt) {
      float qb = q_b[nt * 16 + l15];
#pragma unroll
      for (int r = 0; r < 4; ++r)
        qacc[nt][r] = (qacc[nt][r] + qb) * 0.35355339059327373f;
    }
#pragma unroll
    for (int mt = 0; mt < 4; ++mt)
#pragma unroll
      for (int nt = 0; nt < 4; ++nt) {
        int src = mt * 16 + l15;
        float v0 = __shfl(qacc[nt][0], src);
        float v1 = __shfl(qacc[nt][1], src);
        float v2 = __shfl(qacc[nt][2], src);
        float v3 = __shfl(qacc[nt][3], src);
        float t0 = (quad & 2) ? v2 : v0;
        float t1 = (quad & 2) ? v3 : v1;
        qT[mt][nt] = (quad & 1) ? t1 : t0;
      }
  }

  const int uvl  = l15 & 3;
  const int prow = l15 >> 2;
  const short8* sT = (const short8*)suppT;   // 8 short8 per pixel

  // ---------- K/V + attention, 4 pixels-per-lane per mt iteration (K-dim 64)
  float oreg[4][4];
#pragma unroll
  for (int mt = 0; mt < 4; ++mt) {
    const int gpix = hw0 + wv * 16 + mt * 4 + prow;
    float2 fl = ((const float2*)flow)[b * HWHW + gpix];
    float fy = fl.y + (float)(gpix >> 8);
    float fx = fl.x + (float)(gpix & 255);
    int yy = min(max((int)floorf(fy) + (uvl >> 1), 0), 255);
    int xx = min(max((int)floorf(fx) + (uvl & 1), 0), 255);
    size_t base = (size_t)(b * HWHW + yy * 256 + xx) * 8;

    // A-frag: channels c = ks*32 + quad*8 + j, contiguous bf16 -> dwordx4
    short8 ka0 = sT[base + quad];
    short8 ka1 = sT[base + 4 + quad];

    f32x4 kacc[4], vacc[4];
#pragma unroll
    for (int nt = 0; nt < 4; ++nt) {
      kacc[nt] = (f32x4){0.f, 0.f, 0.f, 0.f};
      vacc[nt] = (f32x4){0.f, 0.f, 0.f, 0.f};
    }
#pragma unroll
    for (int nt = 0; nt < 4; ++nt) {
      kacc[nt] = __builtin_amdgcn_mfma_f32_16x16x32_bf16(
          ka0, wfrag[1024 + nt * 64 + lane], kacc[nt], 0, 0, 0);
      vacc[nt] = __builtin_amdgcn_mfma_f32_16x16x32_bf16(
          ka0, wfrag[1536 + nt * 64 + lane], vacc[nt], 0, 0, 0);
      kacc[nt] = __builtin_amdgcn_mfma_f32_16x16x32_bf16(
          ka1, wfrag[1024 + (4 + nt) * 64 + lane], kacc[nt], 0, 0, 0);
      vacc[nt] = __builtin_amdgcn_mfma_f32_16x16x32_bf16(
          ka1, wfrag[1536 + (4 + nt) * 64 + lane], vacc[nt], 0, 0, 0);
    }

    // D rows: pixel = mt*4+quad, uv = reg r. Head channels span 8 lanes -> xor reduce.
#pragma unroll
    for (int nt = 0; nt < 4; ++nt) {
      float lg[4];
#pragma unroll
      for (int r = 0; r < 4; ++r) {
        float p = qT[mt][nt] * (kacc[nt][r] + kbr[r][nt]);
        p += __shfl_xor(p, 1);
        p += __shfl_xor(p, 2);
        p += __shfl_xor(p, 4);
        lg[r] = p;
      }
      float mx = fmaxf(fmaxf(lg[0], lg[1]), fmaxf(lg[2], lg[3]));
      float e0 = __expf(lg[0] - mx), e1 = __expf(lg[1] - mx);
      float e2 = __expf(lg[2] - mx), e3 = __expf(lg[3] - mx);
      float inv = 1.0f / (e0 + e1 + e2 + e3);
      oreg[mt][nt] = (e0 * (vacc[nt][0] + vbr[0][nt]) + e1 * (vacc[nt][1] + vbr[1][nt]) +
                      e2 * (vacc[nt][2] + vbr[2][nt]) + e3 * (vacc[nt][3] + vbr[3][nt])) * inv;
    }
  }

  // ---------- stage outputs to LDS (alias wfrag), full-line write-out
  __syncthreads();
  float* outstage = (float*)smem;   // [64 ch][65]
#pragma unroll
  for (int mt = 0; mt < 4; ++mt)
#pragma unroll
    for (int nt = 0; nt < 4; ++nt)
      outstage[(nt * 16 + l15) * 65 + wv * 16 + mt * 4 + quad] = oreg[mt][nt];
  __syncthreads();
#pragma unroll
  for (int i = 0; i < 16; ++i) {
    int j = i * 256 + tid;
    int c = j >> 6, p = j & 63;
    out[(b * 64 + c) * HWHW + hw0 + p] = outstage[c * 65 + p];
  }
}

extern "C" void kernel_launch(void* const* d_in, const int* in_sizes, int n_in,
                              void* d_out, int out_size, void* d_ws, size_t ws_size,
                              hipStream_t stream) {
  const float* feat_supp = (const float*)d_in[0];
  const float* flow      = (const float*)d_in[1];
  const float* feat_curr = (const float*)d_in[2];
  const float* q_w = (const float*)d_in[3];
  const float* q_b = (const float*)d_in[4];
  const float* k_w = (const float*)d_in[5];
  const float* k_b = (const float*)d_in[6];
  const float* v_w = (const float*)d_in[7];
  const float* v_b = (const float*)d_in[8];
  float* out = (float*)d_out;
  (void)in_sizes; (void)n_in; (void)out_size; (void)ws_size;

  __hip_bfloat16* wfrag = (__hip_bfloat16*)d_ws;
  float* bias           = (float*)((char*)d_ws + 32768);
  __hip_bfloat16* suppT = (__hip_bfloat16*)((char*)d_ws + 65536);

  hipLaunchKernelGGL(pre_pass, dim3(521), dim3(256), 0, stream,
                     feat_supp, q_w, k_w, v_w, k_b, v_b, suppT, wfrag, bias);
  hipLaunchKernelGGL(iw_main, dim3(2048), dim3(256), 0, stream,
                     suppT, flow, feat_curr, (const f32x4*)d_ws, bias, q_b, out);
}

// Round 8
// 187.663 us; speedup vs baseline: 1.3066x; 1.3066x over previous
//
#include <hip/hip_runtime.h>
#include <hip/hip_bf16.h>

#define HWHW 65536   // 256*256
#define LN1E4_32 0.28782313662425572f   // ln(10000)/32
#define TWO_PI_N 6.2831847f              // 2*pi / 1.000001

typedef __attribute__((ext_vector_type(8))) short short8;
typedef __attribute__((ext_vector_type(4))) short s16x4;   // 'short4' taken by HIP
typedef __attribute__((ext_vector_type(4))) float f32x4;

// d_ws layout:
//   [0, 32768)        : wfrag bf16 — Q slots 0..1023 (K=128), K' 1024..1535,
//                       V' 1536..2047 (K=64, pair-summed weights)
//   [32768, 34816)    : bias tables fp32 — peK·Wk+k_b [4][64], then peV·Wv+v_b
//   [65536, 16842752) : feat_supp transposed (B,HW,C) bf16
// REQUIRES ws_size >= 16842752.

__device__ __forceinline__ short f2bf(float f) {
  union { __hip_bfloat16 h; short s; } u;
  u.h = __float2bfloat16(f);
  return u.s;
}

// ---------------- merged pre-pass:
//   blocks 0..511  : feat_supp (B,C,HW) f32 -> (B,HW,C) bf16 transpose
//   blocks 512..519: weight fragment packing
//   block  520     : PE-folded bias tables
__global__ __launch_bounds__(256)
void pre_pass(const float* __restrict__ supp,
              const float* __restrict__ qw, const float* __restrict__ kw,
              const float* __restrict__ vw,
              const float* __restrict__ kb, const float* __restrict__ vb,
              __hip_bfloat16* __restrict__ suppT,
              __hip_bfloat16* __restrict__ wfrag, float* __restrict__ bias) {
  const int t = threadIdx.x;
  if (blockIdx.x < 512) {
    // ---- transpose: 256 px x 64 ch per block. LDS row stride 68 shorts:
    // 34 dwords -> 4-way max on b64 ops (1.58x) — acceptable.
    __shared__ short tile[256 * 68];
    int b  = blockIdx.x >> 8;
    int p0 = (blockIdx.x & 255) << 8;
#pragma unroll
    for (int cg = 0; cg < 16; ++cg) {
      s16x4 v;
#pragma unroll
      for (int j = 0; j < 4; ++j)
        v[j] = f2bf(supp[((size_t)b * 64 + cg * 4 + j) * HWHW + p0 + t]);
      *(s16x4*)&tile[t * 68 + cg * 4] = v;
    }
    __syncthreads();
#pragma unroll
    for (int i = 0; i < 4; ++i) {
      int pl = i * 64 + (t >> 2);
      int ch = (t & 3) * 16;
      s16x4 r0 = *(s16x4*)&tile[pl * 68 + ch];
      s16x4 r1 = *(s16x4*)&tile[pl * 68 + ch + 4];
      s16x4 r2 = *(s16x4*)&tile[pl * 68 + ch + 8];
      s16x4 r3 = *(s16x4*)&tile[pl * 68 + ch + 12];
      short8 o0, o1;
#pragma unroll
      for (int j = 0; j < 4; ++j) {
        o0[j] = r0[j]; o0[j + 4] = r1[j];
        o1[j] = r2[j]; o1[j + 4] = r3[j];
      }
      short8* dst = (short8*)(suppT + ((size_t)(b * HWHW + p0 + pl)) * 64 + ch);
      dst[0] = o0;
      dst[1] = o1;
    }
  } else if (blockIdx.x < 520) {
    // ---- weight fragments. B layout: n=nt*16+(lane&15), k=ks*32+(lane>>4)*8+j
    int slot = (blockIdx.x - 512) * 256 + t;      // 0..2047
    __hip_bfloat16* dst = wfrag + slot * 8;
    if (slot < 1024) {               // Q (K=128)
      int ksnt = slot >> 6, lane = slot & 63;
      int ks = ksnt >> 2, nt = ksnt & 3;
      const float* w = qw + (nt * 16 + (lane & 15)) * 128 + ks * 32 + (lane >> 4) * 8;
#pragma unroll
      for (int j = 0; j < 8; ++j) dst[j] = __float2bfloat16(w[j]);
    } else {                         // K'/V': K=64, W'[n][c] = W[n][2c]+W[n][2c+1]
      int mat = (slot >= 1536);
      int rem = slot & 511;
      int ksnt = rem >> 6, lane = rem & 63;
      int ks = ksnt >> 2, nt = ksnt & 3;          // ks 0..1
      int c0 = ks * 32 + (lane >> 4) * 8;
      const float* w = (mat ? vw : kw) + (nt * 16 + (lane & 15)) * 128;
#pragma unroll
      for (int j = 0; j < 8; ++j)
        dst[j] = __float2bfloat16(w[2 * (c0 + j)] + w[2 * (c0 + j) + 1]);
    }
  } else {
    // ---- bias[mat*256 + uv*64 + c] = b[c] + sum_kk pe[uv][kk] * W[c][kk]
    for (int s = t; s < 512; s += 256) {
      int mat = s >> 8, uv = (s >> 6) & 3, c = s & 63;
      const float* w = (mat ? vw : kw) + c * 128;
      float acc = (mat ? vb : kb)[c];
      for (int kk = 0; kk < 128; ++kk) {
        float val = (kk < 64 ? (float)(uv >> 1) : (float)(uv & 1)) * TWO_PI_N;
        int i = kk & 63, f = i >> 1;
        float arg = val * __expf(-(float)f * LN1E4_32);
        float pe = (i & 1) ? __cosf(arg) : __sinf(arg);
        acc += pe * w[kk];
      }
      bias[s] = acc;
    }
  }
}

// ---------------- main: 64 px/block, 4 waves. NO LDS in compute path:
// all weight fragments are per-lane-fixed slots (slot*64+lane) -> loaded
// straight from global (L2-resident 32 KB) into registers. LDS = 16.6 KB
// outstage only; one barrier pair at the end.
// waves_per_eu(3,3): proven no-spill (R5: VGPR 84 clean). (4,4) spilled
// 220 MB scratch (R7, VGPR 64); unbounded spilled 580 MB (R2/R3).
__global__ __attribute__((amdgpu_waves_per_eu(3, 3))) __launch_bounds__(256)
void iw_main(const __hip_bfloat16* __restrict__ suppT, const float* __restrict__ flow,
             const float* __restrict__ feat_curr,
             const short8* __restrict__ wg, const float* __restrict__ bias_g,
             const float* __restrict__ q_b, float* __restrict__ out)
{
  __shared__ float outstage[64 * 65];   // 16.6 KB, padded stride 65

  const int tid = threadIdx.x;
  const int idx = ((blockIdx.x & 7) << 8) | (blockIdx.x >> 3);  // XCD swizzle
  const int b   = idx >> 10;
  const int hw0 = (idx & 1023) << 6;
  const int lane = tid & 63, wv = tid >> 6;
  const int quad = lane >> 4, l15 = lane & 15;

  // per-lane inverse dim_t: f = a*16 + quad*4 + jj
  float invd[2][4];
#pragma unroll
  for (int a = 0; a < 2; ++a)
#pragma unroll
    for (int jj = 0; jj < 4; ++jj)
      invd[a][jj] = __expf(-(float)(a * 16 + quad * 4 + jj) * LN1E4_32);

  // ---------- Q phase: A-frag (m = l15 -> pixel), GEMM (K=128), B from global
  f32x4 qacc[4];
  {
    short8 qwf[16];
#pragma unroll
    for (int i = 0; i < 16; ++i) qwf[i] = wg[i * 64 + lane];

    const int qpix = hw0 + wv * 16 + l15;
    float2 fl = ((const float2*)flow)[b * HWHW + qpix];
    float gy = (float)(qpix >> 8) + fl.y;
    float gx = (float)(qpix & 255) + fl.x;
    float vy = (gy - floorf(gy)) * (6.2831853071795864f / 2.000001f);
    float vx = (gx - floorf(gx)) * (6.2831853071795864f / 2.000001f);

    short8 qa[4];
#pragma unroll
    for (int ks = 0; ks < 4; ++ks) {
      float val = (ks < 2) ? vy : vx;
#pragma unroll
      for (int jj = 0; jj < 4; ++jj) {
        int c = ks * 16 + quad * 4 + jj;
        float feat = feat_curr[(b * 64 + c) * HWHW + qpix];
        float arg = val * invd[ks & 1][jj];
        qa[ks][jj * 2]     = f2bf(feat + __sinf(arg));
        qa[ks][jj * 2 + 1] = f2bf(feat + __cosf(arg));
      }
    }
#pragma unroll
    for (int nt = 0; nt < 4; ++nt) qacc[nt] = (f32x4){0.f, 0.f, 0.f, 0.f};
#pragma unroll
    for (int ks = 0; ks < 4; ++ks)
#pragma unroll
      for (int nt = 0; nt < 4; ++nt)
        qacc[nt] = __builtin_amdgcn_mfma_f32_16x16x32_bf16(
            qa[ks], qwf[ks * 4 + nt], qacc[nt], 0, 0, 0);
  }

  // bias+scale then shuffle-transpose: qT[mt][nt] = q[pixel mt*4+quad][nt*16+l15]
  float qT[4][4];
  {
#pragma unroll
    for (int nt = 0; nt < 4; ++nt) {
      float qb = q_b[nt * 16 + l15];
#pragma unroll
      for (int r = 0; r < 4; ++r)
        qacc[nt][r] = (qacc[nt][r] + qb) * 0.35355339059327373f;
    }
#pragma unroll
    for (int mt = 0; mt < 4; ++mt)
#pragma unroll
      for (int nt = 0; nt < 4; ++nt) {
        int src = mt * 16 + l15;
        float v0 = __shfl(qacc[nt][0], src);
        float v1 = __shfl(qacc[nt][1], src);
        float v2 = __shfl(qacc[nt][2], src);
        float v3 = __shfl(qacc[nt][3], src);
        float t0 = (quad & 2) ? v2 : v0;
        float t1 = (quad & 2) ? v3 : v1;
        qT[mt][nt] = (quad & 1) ? t1 : t0;
      }
  }

  // PE-folded K/V biases (regs): kbr[r][nt] for output row uv=r, c=nt*16+l15
  float kbr[4][4], vbr[4][4];
#pragma unroll
  for (int r = 0; r < 4; ++r)
#pragma unroll
    for (int nt = 0; nt < 4; ++nt) {
      kbr[r][nt] = bias_g[r * 64 + nt * 16 + l15];
      vbr[r][nt] = bias_g[256 + r * 64 + nt * 16 + l15];
    }

  // K'/V' B-fragments: per-lane-fixed -> hoist to registers (64 VGPRs)
  short8 kf[8], vf[8];
#pragma unroll
  for (int i = 0; i < 8; ++i) {
    kf[i] = wg[1024 + i * 64 + lane];
    vf[i] = wg[1536 + i * 64 + lane];
  }

  const int uvl  = l15 & 3;
  const int prow = l15 >> 2;
  const short8* sT = (const short8*)suppT;   // 8 short8 per pixel

  // ---------- K/V + attention, 4 pixels-per-lane per mt iteration (K-dim 64)
#pragma unroll
  for (int mt = 0; mt < 4; ++mt) {
    const int gpix = hw0 + wv * 16 + mt * 4 + prow;
    float2 fl = ((const float2*)flow)[b * HWHW + gpix];
    float fy = fl.y + (float)(gpix >> 8);
    float fx = fl.x + (float)(gpix & 255);
    int yy = min(max((int)floorf(fy) + (uvl >> 1), 0), 255);
    int xx = min(max((int)floorf(fx) + (uvl & 1), 0), 255);
    size_t base = (size_t)(b * HWHW + yy * 256 + xx) * 8;

    // A-frag: channels c = ks*32 + quad*8 + j, contiguous bf16 -> dwordx4
    short8 ka0 = sT[base + quad];
    short8 ka1 = sT[base + 4 + quad];

    f32x4 kacc[4], vacc[4];
#pragma unroll
    for (int nt = 0; nt < 4; ++nt) {
      kacc[nt] = (f32x4){0.f, 0.f, 0.f, 0.f};
      vacc[nt] = (f32x4){0.f, 0.f, 0.f, 0.f};
    }
#pragma unroll
    for (int nt = 0; nt < 4; ++nt) {
      kacc[nt] = __builtin_amdgcn_mfma_f32_16x16x32_bf16(ka0, kf[nt],     kacc[nt], 0, 0, 0);
      vacc[nt] = __builtin_amdgcn_mfma_f32_16x16x32_bf16(ka0, vf[nt],     vacc[nt], 0, 0, 0);
      kacc[nt] = __builtin_amdgcn_mfma_f32_16x16x32_bf16(ka1, kf[4 + nt], kacc[nt], 0, 0, 0);
      vacc[nt] = __builtin_amdgcn_mfma_f32_16x16x32_bf16(ka1, vf[4 + nt], vacc[nt], 0, 0, 0);
    }

    // D rows: pixel = mt*4+quad, uv = reg r. Head channels span 8 lanes -> xor reduce.
#pragma unroll
    for (int nt = 0; nt < 4; ++nt) {
      float lg[4];
#pragma unroll
      for (int r = 0; r < 4; ++r) {
        float p = qT[mt][nt] * (kacc[nt][r] + kbr[r][nt]);
        p += __shfl_xor(p, 1);
        p += __shfl_xor(p, 2);
        p += __shfl_xor(p, 4);
        lg[r] = p;
      }
      float mx = fmaxf(fmaxf(lg[0], lg[1]), fmaxf(lg[2], lg[3]));
      float e0 = __expf(lg[0] - mx), e1 = __expf(lg[1] - mx);
      float e2 = __expf(lg[2] - mx), e3 = __expf(lg[3] - mx);
      float inv = 1.0f / (e0 + e1 + e2 + e3);
      float o = (e0 * (vacc[nt][0] + vbr[0][nt]) + e1 * (vacc[nt][1] + vbr[1][nt]) +
                 e2 * (vacc[nt][2] + vbr[2][nt]) + e3 * (vacc[nt][3] + vbr[3][nt])) * inv;
      outstage[(nt * 16 + l15) * 65 + wv * 16 + mt * 4 + quad] = o;
    }
  }

  // ---------- coalesced full-line write-out
  __syncthreads();
#pragma unroll
  for (int i = 0; i < 16; ++i) {
    int j = i * 256 + tid;
    int c = j >> 6, p = j & 63;
    out[(b * 64 + c) * HWHW + hw0 + p] = outstage[c * 65 + p];
  }
}

extern "C" void kernel_launch(void* const* d_in, const int* in_sizes, int n_in,
                              void* d_out, int out_size, void* d_ws, size_t ws_size,
                              hipStream_t stream) {
  const float* feat_supp = (const float*)d_in[0];
  const float* flow      = (const float*)d_in[1];
  const float* feat_curr = (const float*)d_in[2];
  const float* q_w = (const float*)d_in[3];
  const float* q_b = (const float*)d_in[4];
  const float* k_w = (const float*)d_in[5];
  const float* k_b = (const float*)d_in[6];
  const float* v_w = (const float*)d_in[7];
  const float* v_b = (const float*)d_in[8];
  float* out = (float*)d_out;
  (void)in_sizes; (void)n_in; (void)out_size; (void)ws_size;

  __hip_bfloat16* wfrag = (__hip_bfloat16*)d_ws;
  float* bias           = (float*)((char*)d_ws + 32768);
  __hip_bfloat16* suppT = (__hip_bfloat16*)((char*)d_ws + 65536);

  hipLaunchKernelGGL(pre_pass, dim3(521), dim3(256), 0, stream,
                     feat_supp, q_w, k_w, v_w, k_b, v_b, suppT, wfrag, bias);
  hipLaunchKernelGGL(iw_main, dim3(2048), dim3(256), 0, stream,
                     suppT, flow, feat_curr, (const short8*)d_ws, bias, q_b, out);
}